// Round 6
// baseline (143.000 us; speedup 1.0000x reference)
//
#include <hip/hip_runtime.h>

// FinePreprocess, fused-gather MFMA version (no transpose pre-pass).
// B=2, D_F=128, Hf=240, Wf=320, L=4800 (60x80), W=5, stride=4, D_C=256, M=3000.
//
//  prep:  CW[256][128] = down_W^T @ W2^T (f32), cbias[128], W1bf[n][c] bf16
//  t2:    t2[m][o] = c_row[m] @ CW + cbias   (f32, w-invariant term)
//  fine:  out[m][p][o] = sum_c win[p][c]*W1[o][c] + t2[m][o]  via mfma 16x16x32 bf16
//         A gathered DIRECTLY from NCHW fp32 features (8 strided dword loads
//         per fragment, converted f32->bf16 in-register, RNE);
//         B (W1^T) staged in LDS with XOR swizzle for conflict-free reads.
//         Rationale: the old transpose pre-pass moved 157MB HBM at a measured
//         ~3.3 TB/s wall (r3/r4/r5 all stuck) to feed windows covering only
//         ~30% of the map. Direct gather's unique-line working set (~100MB)
//         is L3-resident across replays.

#define HF 240
#define WF 320
#define HWF (HF * WF)
#define LPOS 4800

typedef short short8 __attribute__((ext_vector_type(8)));
typedef float f32x4 __attribute__((ext_vector_type(4)));

__device__ __forceinline__ unsigned short f2bf(float x) {
  union { float f; unsigned u; } v; v.f = x;
  unsigned r = v.u + 0x7FFF + ((v.u >> 16) & 1);  // RNE
  return (unsigned short)(r >> 16);
}

// ---------------- prep: CW, cbias, W1bf ----------------
__global__ __launch_bounds__(256) void prep_kernel(
    const float* __restrict__ down_W, const float* __restrict__ down_b,
    const float* __restrict__ merge_W, const float* __restrict__ merge_b,
    float* __restrict__ CW, float* __restrict__ cbias,
    unsigned short* __restrict__ W1bf) {
  int idx = blockIdx.x * 256 + threadIdx.x;
  if (idx < 32768) {
    int k = idx >> 7, o = idx & 127;  // CW[k][o] = sum_t down_W[t][k]*merge_W[o][128+t]
    float s = 0.f;
    #pragma unroll 4
    for (int t = 0; t < 128; ++t)
      s += down_W[t * 256 + k] * merge_W[o * 256 + 128 + t];
    CW[idx] = s;
  } else if (idx < 49152) {
    int i2 = idx - 32768;
    int n = i2 >> 7, c = i2 & 127;
    W1bf[i2] = f2bf(merge_W[n * 256 + c]);  // W1bf[n][c]
  } else if (idx < 49280) {
    int o = idx - 49152;
    float s = merge_b[o];
    #pragma unroll 4
    for (int t = 0; t < 128; ++t)
      s += down_b[t] * merge_W[o * 256 + 128 + t];
    cbias[o] = s;
  }
}

// ---------------- t2: coarse path (f32, proven) ----------------
__global__ __launch_bounds__(256) void t2_kernel(
    const float* __restrict__ c0, const float* __restrict__ c1,
    const int* __restrict__ b_ids, const int* __restrict__ i_ids,
    const int* __restrict__ j_ids,
    const float* __restrict__ CW, const float* __restrict__ cbias,
    float* __restrict__ t2, int M) {
  __shared__ float crow[8][256];
  const int t = threadIdx.x;
  const int m0 = blockIdx.x * 8;
  const int M2 = 2 * M;
  #pragma unroll
  for (int it = 0; it < 8; ++it) {
    int m = m0 + it;
    float v = 0.f;
    if (m < M2) {
      int b, pos;
      const float* src;
      if (m < M) { b = b_ids[m]; pos = i_ids[m]; src = c0; }
      else       { b = b_ids[m - M]; pos = j_ids[m - M]; src = c1; }
      v = src[((size_t)b * LPOS + pos) * 256 + t];
    }
    crow[it][t] = v;
  }
  __syncthreads();
  const int o = t & 127, half = t >> 7;
  const int r0 = half * 4;
  float a0 = 0.f, a1 = 0.f, a2 = 0.f, a3 = 0.f;
  #pragma unroll 4
  for (int k = 0; k < 256; ++k) {
    float wv = CW[k * 128 + o];
    a0 += crow[r0 + 0][k] * wv;
    a1 += crow[r0 + 1][k] * wv;
    a2 += crow[r0 + 2][k] * wv;
    a3 += crow[r0 + 3][k] * wv;
  }
  const float cb = cbias[o];
  if (m0 + r0 + 0 < M2) t2[(size_t)(m0 + r0 + 0) * 128 + o] = a0 + cb;
  if (m0 + r0 + 1 < M2) t2[(size_t)(m0 + r0 + 1) * 128 + o] = a1 + cb;
  if (m0 + r0 + 2 < M2) t2[(size_t)(m0 + r0 + 2) * 128 + o] = a2 + cb;
  if (m0 + r0 + 3 < M2) t2[(size_t)(m0 + r0 + 3) * 128 + o] = a3 + cb;
}

// ---------------- fine: MFMA with direct NCHW fp32 gather ----------------
// 4 waves/block, 1 m per wave. A gathered global->reg (scalar dword, strided
// by HWF across channels; 16 lanes of an instr walk window pixels -> ~6 lines
// per channel-group); B in swizzled LDS.
__global__ __launch_bounds__(256) void fine_mfma_kernel(
    const float* __restrict__ f0, const float* __restrict__ f1,
    const int* __restrict__ b_ids, const int* __restrict__ i_ids,
    const int* __restrict__ j_ids,
    const unsigned short* __restrict__ W1bf, const float* __restrict__ t2,
    float* __restrict__ out, int M) {
  __shared__ unsigned short Bl[128 * 128];  // swizzled [n][c] bf16, 32KB
  const int t = threadIdx.x;

  // stage B: rows n of W1bf, 16B chunks, XOR swizzle kb ^ ((n&7)<<4)
  #pragma unroll
  for (int it = 0; it < 8; ++it) {
    int q = it * 256 + t;
    int n = q >> 4;
    int kb16 = (q & 15) * 16;
    short8 v = *(const short8*)&W1bf[n * 128 + (q & 15) * 8];
    int dstB = n * 256 + (kb16 ^ ((n & 7) << 4));
    *(short8*)((char*)Bl + dstB) = v;
  }

  const int wid = t >> 6, lane = t & 63;
  const int lr = lane & 15, lg = lane >> 4;
  const int m = blockIdx.x * 4 + wid;
  const int M2 = 2 * M;
  const bool active = (m < M2);

  // A-fragments: lane holds window[p = mt*16+lr][k = kk*32 + lg*8 + 0..7]
  // gathered from NCHW fp32: addr = base + c*HWF + px, c = kk*32+lg*8+j.
  short8 a[2][4];
  #pragma unroll
  for (int mt = 0; mt < 2; ++mt)
    #pragma unroll
    for (int kk = 0; kk < 4; ++kk) a[mt][kk] = (short8){};

  if (active) {
    int b, pos;
    const float* src;
    if (m < M) { b = b_ids[m]; pos = i_ids[m]; src = f0; }
    else       { int mm = m - M; b = b_ids[mm]; pos = j_ids[mm]; src = f1; }
    const float* base = src + (size_t)b * 128 * HWF;
    int hc = pos / 80, wc = pos - hc * 80;
    int h0 = hc * 4 - 2, w0 = wc * 4 - 2;
    #pragma unroll
    for (int mt = 0; mt < 2; ++mt) {
      int p = mt * 16 + lr;
      int pr = p / 5;
      int hh = h0 + pr, ww = w0 + (p - pr * 5);
      bool valid = (p < 25) && ((unsigned)hh < (unsigned)HF) && ((unsigned)ww < (unsigned)WF);
      const float* ap = base + (valid ? (hh * WF + ww) : 0) + (size_t)lg * 8 * HWF;
      #pragma unroll
      for (int kk = 0; kk < 4; ++kk) {
        float v[8];
        #pragma unroll
        for (int j = 0; j < 8; ++j)
          v[j] = valid ? ap[((size_t)kk * 32 + j) * HWF] : 0.f;
        short8 fr;
        #pragma unroll
        for (int j = 0; j < 8; ++j) fr[j] = (short)f2bf(v[j]);
        a[mt][kk] = fr;
      }
    }
  }

  __syncthreads();
  if (!active) return;

  f32x4 acc[2][8];
  #pragma unroll
  for (int mt = 0; mt < 2; ++mt)
    #pragma unroll
    for (int nt = 0; nt < 8; ++nt) {
      f32x4 z = {0.f, 0.f, 0.f, 0.f};
      acc[mt][nt] = z;
    }

  #pragma unroll
  for (int nt = 0; nt < 8; ++nt) {
    int n = nt * 16 + lr;
    int kbase = n * 256;
    int sw = (n & 7) << 4;
    short8 bfr[4];
    #pragma unroll
    for (int kk = 0; kk < 4; ++kk) {
      int kb = (kk * 64 + lg * 16) ^ sw;
      bfr[kk] = *(const short8*)((const char*)Bl + kbase + kb);
    }
    #pragma unroll
    for (int kk = 0; kk < 4; ++kk) {
      acc[0][nt] = __builtin_amdgcn_mfma_f32_16x16x32_bf16(a[0][kk], bfr[kk], acc[0][nt], 0, 0, 0);
      acc[1][nt] = __builtin_amdgcn_mfma_f32_16x16x32_bf16(a[1][kk], bfr[kk], acc[1][nt], 0, 0, 0);
    }
  }

  // epilogue: D row = mt*16 + lg*4 + j (skip rows >= 25), col = nt*16 + lr
  const float* t2row = t2 + (size_t)m * 128;
  float* orow = out + (size_t)m * 25 * 128;
  #pragma unroll
  for (int nt = 0; nt < 8; ++nt) {
    int o = nt * 16 + lr;
    float tv = t2row[o];
    #pragma unroll
    for (int mt = 0; mt < 2; ++mt) {
      #pragma unroll
      for (int j = 0; j < 4; ++j) {
        int r = mt * 16 + lg * 4 + j;
        if (r < 25) orow[r * 128 + o] = acc[mt][nt][j] + tv;
      }
    }
  }
}

extern "C" void kernel_launch(void* const* d_in, const int* in_sizes, int n_in,
                              void* d_out, int out_size, void* d_ws, size_t ws_size,
                              hipStream_t stream) {
  const float* f0      = (const float*)d_in[0];
  const float* f1      = (const float*)d_in[1];
  const float* c0      = (const float*)d_in[2];
  const float* c1      = (const float*)d_in[3];
  const int*   b_ids   = (const int*)d_in[6];
  const int*   i_ids   = (const int*)d_in[7];
  const int*   j_ids   = (const int*)d_in[8];
  const float* down_W  = (const float*)d_in[9];
  const float* down_b  = (const float*)d_in[10];
  const float* merge_W = (const float*)d_in[11];
  const float* merge_b = (const float*)d_in[12];
  const int M = in_sizes[6];
  const int M2 = 2 * M;

  char* wsb = (char*)d_ws;
  float* CW    = (float*)wsb;                 // 131072 B
  float* cbias = (float*)(wsb + 131072);      // 512 B
  float* t2    = (float*)(wsb + 131584);      // 2M*128*4 B
  size_t off = 131584 + (size_t)M2 * 128 * 4;
  off = (off + 255) & ~(size_t)255;
  unsigned short* W1bf = (unsigned short*)(wsb + off);  // 32768 B

  prep_kernel<<<193, 256, 0, stream>>>(down_W, down_b, merge_W, merge_b,
                                       CW, cbias, W1bf);
  t2_kernel<<<(M2 + 7) / 8, 256, 0, stream>>>(c0, c1, b_ids, i_ids, j_ids,
                                              CW, cbias, t2, M);
  fine_mfma_kernel<<<(M2 + 3) / 4, 256, 0, stream>>>(f0, f1, b_ids, i_ids, j_ids,
                                                     W1bf, t2, (float*)d_out, M);
}

// Round 7
// 117.270 us; speedup vs baseline: 1.2194x; 1.2194x over previous
//
#include <hip/hip_runtime.h>

// FinePreprocess: sparse transpose + MFMA fine. B=2, D_F=128, Hf=240, Wf=320,
// L=4800 (60x80), W=5, stride=4, D_C=256, M=3000.
//
//  mask:      touched-cell bitmap [map*2+b][4800] from b/i/j ids (rebuilt per call).
//  transpose: feat [b][c][h][w] f32 -> tmap [b][c8][pix][8ch] bf16, but ONLY for
//             pixels covered by >=1 touched cell's 5x5 window (~39% of pixels).
//             Uncovered tmap entries are never read by fine (every pixel fine
//             reads lies in a touched cell's window, which is covered).
//  prep:      CW[256][128] = down_W^T @ W2^T (f32), cbias[128], W1bf[n][c] bf16
//  t2:        t2[m][o] = c_row[m] @ CW + cbias   (f32, w-invariant term)
//  fine:      out[m][p][o] = sum_c win[p][c]*W1[o][c] + t2[m][o] via mfma 16x16x32
//             A global->reg in fragment layout from tmap; B in XOR-swizzled LDS.

#define HF 240
#define WF 320
#define HWF (HF * WF)
#define LPOS 4800

typedef short short8 __attribute__((ext_vector_type(8)));
typedef unsigned short ushort8 __attribute__((ext_vector_type(8)));
typedef float f32x4 __attribute__((ext_vector_type(4)));

__device__ __forceinline__ unsigned short f2bf(float x) {
  union { float f; unsigned u; } v; v.f = x;
  unsigned r = v.u + 0x7FFF + ((v.u >> 16) & 1);  // RNE
  return (unsigned short)(r >> 16);
}

// ---------------- mask: touched-cell bitmap ----------------
// Single block; zero 4*4800 bytes then scatter 2M ones. Benign same-value races.
__global__ __launch_bounds__(256) void mask_kernel(
    const int* __restrict__ b_ids, const int* __restrict__ i_ids,
    const int* __restrict__ j_ids, unsigned char* __restrict__ mask, int M) {
  const int t = threadIdx.x;
  int* m4 = (int*)mask;
  for (int i = t; i < 4800; i += 256) m4[i] = 0;  // 19200 B
  __syncthreads();
  const int M2 = 2 * M;
  for (int m = t; m < M2; m += 256) {
    int map, b, pos;
    if (m < M) { map = 0; b = b_ids[m]; pos = i_ids[m]; }
    else       { map = 1; b = b_ids[m - M]; pos = j_ids[m - M]; }
    mask[(map * 2 + b) * LPOS + pos] = 1;
  }
}

// ---------------- sparse transpose + bf16 convert ----------------
// grid (300, 16, 4): x = 256-pixel tile, y = c8 plane, z = map*2+b.
// Thread: one pixel, 8 channels. Early-out if pixel not covered by any
// touched cell (candidates: hc in {(h+1)>>2, (h+2)>>2}, wc likewise).
__global__ __launch_bounds__(256) void transpose_kernel(
    const float* __restrict__ f0, const float* __restrict__ f1,
    unsigned short* __restrict__ t0, unsigned short* __restrict__ t1,
    const unsigned char* __restrict__ mask) {
  const int t = threadIdx.x;
  const int px = blockIdx.x * 256 + t;
  const int c8 = blockIdx.y;
  const int mb = blockIdx.z;  // map*2 + b

  const int h = px / WF, w = px - h * WF;
  // cell candidates whose 5x5 window (center 4hc..4hc+3 area, rows 4hc-2..4hc+2)
  // contains this pixel: (h-2)/4 <= hc <= (h+2)/4
  int hc_lo = (h >= 2) ? ((h + 1) >> 2) : 0;
  int hc_hi = (h + 2) >> 2; if (hc_hi > 59) hc_hi = 59;
  int wc_lo = (w >= 2) ? ((w + 1) >> 2) : 0;
  int wc_hi = (w + 2) >> 2; if (wc_hi > 79) wc_hi = 79;
  const unsigned char* mk = mask + mb * LPOS;
  bool covered = false;
  for (int hc = hc_lo; hc <= hc_hi; ++hc)
    for (int wc = wc_lo; wc <= wc_hi; ++wc)
      covered |= (mk[hc * 80 + wc] != 0);
  if (!covered) return;

  const float* src = ((mb >> 1) ? f1 : f0)
                   + ((size_t)(mb & 1) * 128 + (size_t)c8 * 8) * HWF + px;
  unsigned short* dst = ((mb >> 1) ? t1 : t0)
                      + (((size_t)(mb & 1) * 16 + (size_t)c8) * HWF + px) * 8;

  float v[8];
  #pragma unroll
  for (int j = 0; j < 8; ++j) v[j] = src[(size_t)j * HWF];
  ushort8 u;
  #pragma unroll
  for (int j = 0; j < 8; ++j) u[j] = f2bf(v[j]);
  *(ushort8*)dst = u;  // 16B/lane
}

// ---------------- prep: CW, cbias, W1bf ----------------
__global__ __launch_bounds__(256) void prep_kernel(
    const float* __restrict__ down_W, const float* __restrict__ down_b,
    const float* __restrict__ merge_W, const float* __restrict__ merge_b,
    float* __restrict__ CW, float* __restrict__ cbias,
    unsigned short* __restrict__ W1bf) {
  int idx = blockIdx.x * 256 + threadIdx.x;
  if (idx < 32768) {
    int k = idx >> 7, o = idx & 127;  // CW[k][o] = sum_t down_W[t][k]*merge_W[o][128+t]
    float s = 0.f;
    #pragma unroll 4
    for (int t = 0; t < 128; ++t)
      s += down_W[t * 256 + k] * merge_W[o * 256 + 128 + t];
    CW[idx] = s;
  } else if (idx < 49152) {
    int i2 = idx - 32768;
    int n = i2 >> 7, c = i2 & 127;
    W1bf[i2] = f2bf(merge_W[n * 256 + c]);  // W1bf[n][c]
  } else if (idx < 49280) {
    int o = idx - 49152;
    float s = merge_b[o];
    #pragma unroll 4
    for (int t = 0; t < 128; ++t)
      s += down_b[t] * merge_W[o * 256 + 128 + t];
    cbias[o] = s;
  }
}

// ---------------- t2: coarse path (f32, proven) ----------------
__global__ __launch_bounds__(256) void t2_kernel(
    const float* __restrict__ c0, const float* __restrict__ c1,
    const int* __restrict__ b_ids, const int* __restrict__ i_ids,
    const int* __restrict__ j_ids,
    const float* __restrict__ CW, const float* __restrict__ cbias,
    float* __restrict__ t2, int M) {
  __shared__ float crow[8][256];
  const int t = threadIdx.x;
  const int m0 = blockIdx.x * 8;
  const int M2 = 2 * M;
  #pragma unroll
  for (int it = 0; it < 8; ++it) {
    int m = m0 + it;
    float v = 0.f;
    if (m < M2) {
      int b, pos;
      const float* src;
      if (m < M) { b = b_ids[m]; pos = i_ids[m]; src = c0; }
      else       { b = b_ids[m - M]; pos = j_ids[m - M]; src = c1; }
      v = src[((size_t)b * LPOS + pos) * 256 + t];
    }
    crow[it][t] = v;
  }
  __syncthreads();
  const int o = t & 127, half = t >> 7;
  const int r0 = half * 4;
  float a0 = 0.f, a1 = 0.f, a2 = 0.f, a3 = 0.f;
  #pragma unroll 4
  for (int k = 0; k < 256; ++k) {
    float wv = CW[k * 128 + o];
    a0 += crow[r0 + 0][k] * wv;
    a1 += crow[r0 + 1][k] * wv;
    a2 += crow[r0 + 2][k] * wv;
    a3 += crow[r0 + 3][k] * wv;
  }
  const float cb = cbias[o];
  if (m0 + r0 + 0 < M2) t2[(size_t)(m0 + r0 + 0) * 128 + o] = a0 + cb;
  if (m0 + r0 + 1 < M2) t2[(size_t)(m0 + r0 + 1) * 128 + o] = a1 + cb;
  if (m0 + r0 + 2 < M2) t2[(size_t)(m0 + r0 + 2) * 128 + o] = a2 + cb;
  if (m0 + r0 + 3 < M2) t2[(size_t)(m0 + r0 + 3) * 128 + o] = a3 + cb;
}

// ---------------- fine: MFMA ----------------
// 4 waves/block, 1 m per wave. A global->reg in frag layout; B in swizzled LDS.
__global__ __launch_bounds__(256) void fine_mfma_kernel(
    const unsigned short* __restrict__ t0, const unsigned short* __restrict__ t1,
    const int* __restrict__ b_ids, const int* __restrict__ i_ids,
    const int* __restrict__ j_ids,
    const unsigned short* __restrict__ W1bf, const float* __restrict__ t2,
    float* __restrict__ out, int M) {
  __shared__ unsigned short Bl[128 * 128];  // swizzled [n][c] bf16, 32KB
  const int t = threadIdx.x;

  // stage B: rows n of W1bf, 16B chunks, XOR swizzle kb ^ ((n&7)<<4)
  #pragma unroll
  for (int it = 0; it < 8; ++it) {
    int q = it * 256 + t;
    int n = q >> 4;
    int kb16 = (q & 15) * 16;
    short8 v = *(const short8*)&W1bf[n * 128 + (q & 15) * 8];
    int dstB = n * 256 + (kb16 ^ ((n & 7) << 4));
    *(short8*)((char*)Bl + dstB) = v;
  }

  const int wid = t >> 6, lane = t & 63;
  const int lr = lane & 15, lg = lane >> 4;
  const int m = blockIdx.x * 4 + wid;
  const int M2 = 2 * M;
  const bool active = (m < M2);

  // A-fragments: lane holds window[p = mt*16+lr][k = kk*32 + lg*8 + 0..7]
  // tmap layout [b][c8][pix][8]: channels kk*32+lg*8.. are plane c8=kk*4+lg.
  short8 a[2][4];
  short8 az = {};
  if (active) {
    int b, pos;
    const unsigned short* tm;
    if (m < M) { b = b_ids[m]; pos = i_ids[m]; tm = t0; }
    else       { int mm = m - M; b = b_ids[mm]; pos = j_ids[mm]; tm = t1; }
    tm += (size_t)b * 16 * HWF * 8;
    int hc = pos / 80, wc = pos - hc * 80;
    int h0 = hc * 4 - 2, w0 = wc * 4 - 2;
    #pragma unroll
    for (int mt = 0; mt < 2; ++mt) {
      int p = mt * 16 + lr;
      int pr = p / 5;
      int hh = h0 + pr, ww = w0 + (p - pr * 5);
      bool valid = (p < 25) && ((unsigned)hh < (unsigned)HF) && ((unsigned)ww < (unsigned)WF);
      int px = valid ? (hh * WF + ww) : 0;
      #pragma unroll
      for (int kk = 0; kk < 4; ++kk) {
        const short8* ap =
            (const short8*)(tm + (((size_t)(kk * 4 + lg) * HWF + px) << 3));
        a[mt][kk] = valid ? *ap : az;
      }
    }
  } else {
    #pragma unroll
    for (int mt = 0; mt < 2; ++mt)
      #pragma unroll
      for (int kk = 0; kk < 4; ++kk) a[mt][kk] = az;
  }

  __syncthreads();
  if (!active) return;

  f32x4 acc[2][8];
  #pragma unroll
  for (int mt = 0; mt < 2; ++mt)
    #pragma unroll
    for (int nt = 0; nt < 8; ++nt) {
      f32x4 z = {0.f, 0.f, 0.f, 0.f};
      acc[mt][nt] = z;
    }

  #pragma unroll
  for (int nt = 0; nt < 8; ++nt) {
    int n = nt * 16 + lr;
    int kbase = n * 256;
    int sw = (n & 7) << 4;
    short8 bfr[4];
    #pragma unroll
    for (int kk = 0; kk < 4; ++kk) {
      int kb = (kk * 64 + lg * 16) ^ sw;
      bfr[kk] = *(const short8*)((const char*)Bl + kbase + kb);
    }
    #pragma unroll
    for (int kk = 0; kk < 4; ++kk) {
      acc[0][nt] = __builtin_amdgcn_mfma_f32_16x16x32_bf16(a[0][kk], bfr[kk], acc[0][nt], 0, 0, 0);
      acc[1][nt] = __builtin_amdgcn_mfma_f32_16x16x32_bf16(a[1][kk], bfr[kk], acc[1][nt], 0, 0, 0);
    }
  }

  // epilogue: D row = mt*16 + lg*4 + j (skip rows >= 25), col = nt*16 + lr
  const float* t2row = t2 + (size_t)m * 128;
  float* orow = out + (size_t)m * 25 * 128;
  #pragma unroll
  for (int nt = 0; nt < 8; ++nt) {
    int o = nt * 16 + lr;
    float tv = t2row[o];
    #pragma unroll
    for (int mt = 0; mt < 2; ++mt) {
      #pragma unroll
      for (int j = 0; j < 4; ++j) {
        int r = mt * 16 + lg * 4 + j;
        if (r < 25) orow[r * 128 + o] = acc[mt][nt][j] + tv;
      }
    }
  }
}

extern "C" void kernel_launch(void* const* d_in, const int* in_sizes, int n_in,
                              void* d_out, int out_size, void* d_ws, size_t ws_size,
                              hipStream_t stream) {
  const float* f0      = (const float*)d_in[0];
  const float* f1      = (const float*)d_in[1];
  const float* c0      = (const float*)d_in[2];
  const float* c1      = (const float*)d_in[3];
  const int*   b_ids   = (const int*)d_in[6];
  const int*   i_ids   = (const int*)d_in[7];
  const int*   j_ids   = (const int*)d_in[8];
  const float* down_W  = (const float*)d_in[9];
  const float* down_b  = (const float*)d_in[10];
  const float* merge_W = (const float*)d_in[11];
  const float* merge_b = (const float*)d_in[12];
  const int M = in_sizes[6];
  const int M2 = 2 * M;

  char* wsb = (char*)d_ws;
  float* CW    = (float*)wsb;                 // 131072 B
  float* cbias = (float*)(wsb + 131072);      // 512 B
  float* t2    = (float*)(wsb + 131584);      // 2M*128*4 B
  size_t off = 131584 + (size_t)M2 * 128 * 4;
  off = (off + 255) & ~(size_t)255;
  unsigned short* W1bf = (unsigned short*)(wsb + off);  // 32768 B
  off += 32768;
  unsigned char* mask = (unsigned char*)(wsb + off);    // 19200 B
  off += 19456;
  unsigned short* t0 = (unsigned short*)(wsb + off);    // 2*16*HWF*8*2 B
  off += (size_t)2 * 16 * HWF * 8 * 2;
  unsigned short* t1 = (unsigned short*)(wsb + off);

  mask_kernel<<<1, 256, 0, stream>>>(b_ids, i_ids, j_ids, mask, M);
  prep_kernel<<<193, 256, 0, stream>>>(down_W, down_b, merge_W, merge_b,
                                       CW, cbias, W1bf);
  transpose_kernel<<<dim3(300, 16, 4), 256, 0, stream>>>(f0, f1, t0, t1, mask);
  t2_kernel<<<(M2 + 7) / 8, 256, 0, stream>>>(c0, c1, b_ids, i_ids, j_ids,
                                              CW, cbias, t2, M);
  fine_mfma_kernel<<<(M2 + 3) / 4, 256, 0, stream>>>(t0, t1, b_ids, i_ids, j_ids,
                                                     W1bf, t2, (float*)d_out, M);
}

// Round 8
// 115.346 us; speedup vs baseline: 1.2397x; 1.0167x over previous
//
#include <hip/hip_runtime.h>

// FinePreprocess, MFMA version, plane-tiled bf16 feature maps.
// B=2, D_F=128, Hf=240, Wf=320, L=4800 (60x80), W=5, stride=4, D_C=256, M=3000.
//
//  transpose: feat [b][c][h][w] f32 -> tmap [b][c8][pix][8ch] bf16.
//             Block-cooperative plane-major streaming: each block owns a
//             3072-px span of one (c8,mb) plane-group. Phase A: 8 planes read
//             plane-by-plane, 12KB contiguous per plane per block (3 float4
//             per thread), bf16 into LDS [8][3072]. Phase B: [px][8ch]
//             interleave written as one 48KB contiguous block store.
//             Tests the DRAM page/stream-locality theory for the ~66us wall.
//  prep:      CW[256][128] = down_W^T @ W2^T (f32), cbias[128], W1bf[n][c] bf16
//  t2:        t2[m][o] = c_row[m] @ CW + cbias   (f32, w-invariant term)
//  fine:      out[m][p][o] = sum_c win[p][c]*W1[o][c] + t2[m][o] via mfma 16x16x32
//             A global->reg in frag layout from tmap; B in XOR-swizzled LDS.

#define HF 240
#define WF 320
#define HWF (HF * WF)
#define LPOS 4800

typedef short short8 __attribute__((ext_vector_type(8)));
typedef unsigned short ushort8 __attribute__((ext_vector_type(8)));
typedef float f32x4 __attribute__((ext_vector_type(4)));

__device__ __forceinline__ unsigned short f2bf(float x) {
  union { float f; unsigned u; } v; v.f = x;
  unsigned r = v.u + 0x7FFF + ((v.u >> 16) & 1);  // RNE
  return (unsigned short)(r >> 16);
}

// ---------------- transpose: plane-major streaming ----------------
// grid (25, 16, 4): x = 3072-px span, y = c8 plane-group, z = map*2+b.
__global__ __launch_bounds__(256) void transpose_kernel(
    const float* __restrict__ f0, const float* __restrict__ f1,
    unsigned short* __restrict__ t0, unsigned short* __restrict__ t1) {
  __shared__ unsigned short tile[8][3072];  // 48KB
  const int t = threadIdx.x;
  const int px0 = blockIdx.x * 3072;
  const int c8 = blockIdx.y;
  const int mb = blockIdx.z;  // map*2 + b
  const float* src = ((mb >> 1) ? f1 : f0)
                   + ((size_t)(mb & 1) * 128 + (size_t)c8 * 8) * HWF + px0;
  unsigned short* dst = ((mb >> 1) ? t1 : t0)
                      + (((size_t)(mb & 1) * 16 + (size_t)c8) * HWF + px0) * 8;

  // Phase A: plane-major. Per plane: 3 float4/thread = 12KB contiguous/block.
  float4 v[8][3];
  #pragma unroll
  for (int j = 0; j < 8; ++j)
    #pragma unroll
    for (int i = 0; i < 3; ++i)
      v[j][i] = *(const float4*)&src[(size_t)j * HWF + (i * 256 + t) * 4];

  #pragma unroll
  for (int j = 0; j < 8; ++j)
    #pragma unroll
    for (int i = 0; i < 3; ++i) {
      ushort4 u;
      u.x = f2bf(v[j][i].x); u.y = f2bf(v[j][i].y);
      u.z = f2bf(v[j][i].z); u.w = f2bf(v[j][i].w);
      *(ushort4*)&tile[j][(i * 256 + t) * 4] = u;  // 2-way bank alias: free
    }
  __syncthreads();

  // Phase B: [px][8ch] gather; block writes 48KB contiguous.
  #pragma unroll
  for (int i = 0; i < 12; ++i) {
    int p = i * 256 + t;
    ushort8 u;
    #pragma unroll
    for (int j = 0; j < 8; ++j) u[j] = tile[j][p];  // 2B-stride lanes: conflict-free
    *(ushort8*)&dst[(size_t)p * 8] = u;  // 1KB/wave-instr contiguous
  }
}

// ---------------- prep: CW, cbias, W1bf ----------------
__global__ __launch_bounds__(256) void prep_kernel(
    const float* __restrict__ down_W, const float* __restrict__ down_b,
    const float* __restrict__ merge_W, const float* __restrict__ merge_b,
    float* __restrict__ CW, float* __restrict__ cbias,
    unsigned short* __restrict__ W1bf) {
  int idx = blockIdx.x * 256 + threadIdx.x;
  if (idx < 32768) {
    int k = idx >> 7, o = idx & 127;  // CW[k][o] = sum_t down_W[t][k]*merge_W[o][128+t]
    float s = 0.f;
    #pragma unroll 4
    for (int t = 0; t < 128; ++t)
      s += down_W[t * 256 + k] * merge_W[o * 256 + 128 + t];
    CW[idx] = s;
  } else if (idx < 49152) {
    int i2 = idx - 32768;
    int n = i2 >> 7, c = i2 & 127;
    W1bf[i2] = f2bf(merge_W[n * 256 + c]);  // W1bf[n][c]
  } else if (idx < 49280) {
    int o = idx - 49152;
    float s = merge_b[o];
    #pragma unroll 4
    for (int t = 0; t < 128; ++t)
      s += down_b[t] * merge_W[o * 256 + 128 + t];
    cbias[o] = s;
  }
}

// ---------------- t2: coarse path (f32, proven) ----------------
__global__ __launch_bounds__(256) void t2_kernel(
    const float* __restrict__ c0, const float* __restrict__ c1,
    const int* __restrict__ b_ids, const int* __restrict__ i_ids,
    const int* __restrict__ j_ids,
    const float* __restrict__ CW, const float* __restrict__ cbias,
    float* __restrict__ t2, int M) {
  __shared__ float crow[8][256];
  const int t = threadIdx.x;
  const int m0 = blockIdx.x * 8;
  const int M2 = 2 * M;
  #pragma unroll
  for (int it = 0; it < 8; ++it) {
    int m = m0 + it;
    float v = 0.f;
    if (m < M2) {
      int b, pos;
      const float* src;
      if (m < M) { b = b_ids[m]; pos = i_ids[m]; src = c0; }
      else       { b = b_ids[m - M]; pos = j_ids[m - M]; src = c1; }
      v = src[((size_t)b * LPOS + pos) * 256 + t];
    }
    crow[it][t] = v;
  }
  __syncthreads();
  const int o = t & 127, half = t >> 7;
  const int r0 = half * 4;
  float a0 = 0.f, a1 = 0.f, a2 = 0.f, a3 = 0.f;
  #pragma unroll 4
  for (int k = 0; k < 256; ++k) {
    float wv = CW[k * 128 + o];
    a0 += crow[r0 + 0][k] * wv;
    a1 += crow[r0 + 1][k] * wv;
    a2 += crow[r0 + 2][k] * wv;
    a3 += crow[r0 + 3][k] * wv;
  }
  const float cb = cbias[o];
  if (m0 + r0 + 0 < M2) t2[(size_t)(m0 + r0 + 0) * 128 + o] = a0 + cb;
  if (m0 + r0 + 1 < M2) t2[(size_t)(m0 + r0 + 1) * 128 + o] = a1 + cb;
  if (m0 + r0 + 2 < M2) t2[(size_t)(m0 + r0 + 2) * 128 + o] = a2 + cb;
  if (m0 + r0 + 3 < M2) t2[(size_t)(m0 + r0 + 3) * 128 + o] = a3 + cb;
}

// ---------------- fine: MFMA ----------------
// 4 waves/block, 1 m per wave. A global->reg in frag layout; B in swizzled LDS.
__global__ __launch_bounds__(256) void fine_mfma_kernel(
    const unsigned short* __restrict__ t0, const unsigned short* __restrict__ t1,
    const int* __restrict__ b_ids, const int* __restrict__ i_ids,
    const int* __restrict__ j_ids,
    const unsigned short* __restrict__ W1bf, const float* __restrict__ t2,
    float* __restrict__ out, int M) {
  __shared__ unsigned short Bl[128 * 128];  // swizzled [n][c] bf16, 32KB
  const int t = threadIdx.x;

  // stage B: rows n of W1bf, 16B chunks, XOR swizzle kb ^ ((n&7)<<4)
  #pragma unroll
  for (int it = 0; it < 8; ++it) {
    int q = it * 256 + t;
    int n = q >> 4;
    int kb16 = (q & 15) * 16;
    short8 v = *(const short8*)&W1bf[n * 128 + (q & 15) * 8];
    int dstB = n * 256 + (kb16 ^ ((n & 7) << 4));
    *(short8*)((char*)Bl + dstB) = v;
  }

  const int wid = t >> 6, lane = t & 63;
  const int lr = lane & 15, lg = lane >> 4;
  const int m = blockIdx.x * 4 + wid;
  const int M2 = 2 * M;
  const bool active = (m < M2);

  // A-fragments: lane holds window[p = mt*16+lr][k = kk*32 + lg*8 + 0..7]
  // tmap layout [b][c8][pix][8]: channels kk*32+lg*8.. are plane c8=kk*4+lg.
  short8 a[2][4];
  short8 az = {};
  if (active) {
    int b, pos;
    const unsigned short* tm;
    if (m < M) { b = b_ids[m]; pos = i_ids[m]; tm = t0; }
    else       { int mm = m - M; b = b_ids[mm]; pos = j_ids[mm]; tm = t1; }
    tm += (size_t)b * 16 * HWF * 8;
    int hc = pos / 80, wc = pos - hc * 80;
    int h0 = hc * 4 - 2, w0 = wc * 4 - 2;
    #pragma unroll
    for (int mt = 0; mt < 2; ++mt) {
      int p = mt * 16 + lr;
      int pr = p / 5;
      int hh = h0 + pr, ww = w0 + (p - pr * 5);
      bool valid = (p < 25) && ((unsigned)hh < (unsigned)HF) && ((unsigned)ww < (unsigned)WF);
      int px = valid ? (hh * WF + ww) : 0;
      #pragma unroll
      for (int kk = 0; kk < 4; ++kk) {
        const short8* ap =
            (const short8*)(tm + (((size_t)(kk * 4 + lg) * HWF + px) << 3));
        a[mt][kk] = valid ? *ap : az;
      }
    }
  } else {
    #pragma unroll
    for (int mt = 0; mt < 2; ++mt)
      #pragma unroll
      for (int kk = 0; kk < 4; ++kk) a[mt][kk] = az;
  }

  __syncthreads();
  if (!active) return;

  f32x4 acc[2][8];
  #pragma unroll
  for (int mt = 0; mt < 2; ++mt)
    #pragma unroll
    for (int nt = 0; nt < 8; ++nt) {
      f32x4 z = {0.f, 0.f, 0.f, 0.f};
      acc[mt][nt] = z;
    }

  #pragma unroll
  for (int nt = 0; nt < 8; ++nt) {
    int n = nt * 16 + lr;
    int kbase = n * 256;
    int sw = (n & 7) << 4;
    short8 bfr[4];
    #pragma unroll
    for (int kk = 0; kk < 4; ++kk) {
      int kb = (kk * 64 + lg * 16) ^ sw;
      bfr[kk] = *(const short8*)((const char*)Bl + kbase + kb);
    }
    #pragma unroll
    for (int kk = 0; kk < 4; ++kk) {
      acc[0][nt] = __builtin_amdgcn_mfma_f32_16x16x32_bf16(a[0][kk], bfr[kk], acc[0][nt], 0, 0, 0);
      acc[1][nt] = __builtin_amdgcn_mfma_f32_16x16x32_bf16(a[1][kk], bfr[kk], acc[1][nt], 0, 0, 0);
    }
  }

  // epilogue: D row = mt*16 + lg*4 + j (skip rows >= 25), col = nt*16 + lr
  const float* t2row = t2 + (size_t)m * 128;
  float* orow = out + (size_t)m * 25 * 128;
  #pragma unroll
  for (int nt = 0; nt < 8; ++nt) {
    int o = nt * 16 + lr;
    float tv = t2row[o];
    #pragma unroll
    for (int mt = 0; mt < 2; ++mt) {
      #pragma unroll
      for (int j = 0; j < 4; ++j) {
        int r = mt * 16 + lg * 4 + j;
        if (r < 25) orow[r * 128 + o] = acc[mt][nt][j] + tv;
      }
    }
  }
}

extern "C" void kernel_launch(void* const* d_in, const int* in_sizes, int n_in,
                              void* d_out, int out_size, void* d_ws, size_t ws_size,
                              hipStream_t stream) {
  const float* f0      = (const float*)d_in[0];
  const float* f1      = (const float*)d_in[1];
  const float* c0      = (const float*)d_in[2];
  const float* c1      = (const float*)d_in[3];
  const int*   b_ids   = (const int*)d_in[6];
  const int*   i_ids   = (const int*)d_in[7];
  const int*   j_ids   = (const int*)d_in[8];
  const float* down_W  = (const float*)d_in[9];
  const float* down_b  = (const float*)d_in[10];
  const float* merge_W = (const float*)d_in[11];
  const float* merge_b = (const float*)d_in[12];
  const int M = in_sizes[6];
  const int M2 = 2 * M;

  char* wsb = (char*)d_ws;
  float* CW    = (float*)wsb;                 // 131072 B
  float* cbias = (float*)(wsb + 131072);      // 512 B
  float* t2    = (float*)(wsb + 131584);      // 2M*128*4 B
  size_t off = 131584 + (size_t)M2 * 128 * 4;
  off = (off + 255) & ~(size_t)255;
  unsigned short* W1bf = (unsigned short*)(wsb + off);  // 32768 B
  off += 32768;
  unsigned short* t0 = (unsigned short*)(wsb + off);    // 2*16*HWF*8*2 B
  off += (size_t)2 * 16 * HWF * 8 * 2;
  unsigned short* t1 = (unsigned short*)(wsb + off);

  transpose_kernel<<<dim3(25, 16, 4), 256, 0, stream>>>(f0, f1, t0, t1);
  prep_kernel<<<193, 256, 0, stream>>>(down_W, down_b, merge_W, merge_b,
                                       CW, cbias, W1bf);
  t2_kernel<<<(M2 + 7) / 8, 256, 0, stream>>>(c0, c1, b_ids, i_ids, j_ids,
                                              CW, cbias, t2, M);
  fine_mfma_kernel<<<(M2 + 3) / 4, 256, 0, stream>>>(t0, t1, b_ids, i_ids, j_ids,
                                                     W1bf, t2, (float*)d_out, M);
}

// Round 9
// 108.323 us; speedup vs baseline: 1.3201x; 1.0648x over previous
//
#include <hip/hip_runtime.h>

// FinePreprocess, MFMA version, plane-tiled bf16 feature maps.
// B=2, D_F=128, Hf=240, Wf=320, L=4800 (60x80), W=5, stride=4, D_C=256, M=3000.
//
//  transpose: feat [b][c][h][w] f32 -> tmap [b][c8][pix][8ch] bf16.
//             PERSISTENT + SOFTWARE-PIPELINED (m13 copy structure): 2400 blocks
//             x 8 tiles each; double-buffered loads so tile i+1's 8 strided
//             dword loads are in flight while tile i converts+stores. Fully
//             unrolled -> all buffer indices static (no scratch).
//  prep:      CW[256][128] = down_W^T @ W2^T (f32), cbias[128], W1bf[n][c] bf16
//  t2:        t2[m][o] = c_row[m] @ CW + cbias   (f32, w-invariant term)
//  fine:      out[m][p][o] = sum_c win[p][c]*W1[o][c] + t2[m][o] via mfma 16x16x32.
//             A global->reg in frag layout from tmap; B in XOR-swizzled LDS.
//             d_out stores are NON-TEMPORAL (out is never re-read) so the
//             76.8MB output stream stops evicting input/tmap from the 256MB L3
//             across replays (observed: replay FETCH == write volume).

#define HF 240
#define WF 320
#define HWF (HF * WF)
#define LPOS 4800
#define TPB 8  // tiles per persistent block

typedef short short8 __attribute__((ext_vector_type(8)));
typedef unsigned short ushort8 __attribute__((ext_vector_type(8)));
typedef float f32x4 __attribute__((ext_vector_type(4)));

__device__ __forceinline__ unsigned short f2bf(float x) {
  union { float f; unsigned u; } v; v.f = x;
  unsigned r = v.u + 0x7FFF + ((v.u >> 16) & 1);  // RNE
  return (unsigned short)(r >> 16);
}

// ---------------- transpose: persistent, double-buffered ----------------
// tile id = (mb*16 + c8)*300 + pt ; px = pt*256 + t. 19200 tiles, 2400 blocks.
__global__ __launch_bounds__(256) void transpose_kernel(
    const float* __restrict__ f0, const float* __restrict__ f1,
    unsigned short* __restrict__ t0, unsigned short* __restrict__ t1) {
  const int t = threadIdx.x;
  const int tile0 = blockIdx.x * TPB;

  const float* s[2];
  unsigned short* d[2];
  float v[2][8];

#define ADDR(TILE, SLOT)                                                      \
  {                                                                           \
    int tile = (TILE);                                                        \
    int pt = tile % 300;                                                      \
    int pc = tile / 300;                                                      \
    int c8 = pc & 15, mb = pc >> 4;                                           \
    int px = pt * 256 + t;                                                    \
    s[SLOT] = ((mb >> 1) ? f1 : f0)                                           \
              + ((size_t)(mb & 1) * 128 + (size_t)c8 * 8) * HWF + px;         \
    d[SLOT] = ((mb >> 1) ? t1 : t0)                                           \
              + ((((size_t)(mb & 1) * 16 + c8) * HWF + px) << 3);             \
  }
#define ISSUE(SLOT)                                                           \
  _Pragma("unroll") for (int j = 0; j < 8; ++j)                               \
      v[SLOT][j] = s[SLOT][(size_t)j * HWF];
#define FLUSH(SLOT)                                                           \
  {                                                                           \
    ushort8 u;                                                                \
    _Pragma("unroll") for (int j = 0; j < 8; ++j) u[j] = f2bf(v[SLOT][j]);    \
    *(ushort8*)d[SLOT] = u;                                                   \
  }

  ADDR(tile0, 0)
  ISSUE(0)
  #pragma unroll
  for (int it = 0; it < TPB; ++it) {
    const int cur = it & 1, nxt = cur ^ 1;
    if (it + 1 < TPB) {
      ADDR(tile0 + it + 1, nxt)
      ISSUE(nxt)   // next tile's loads in flight while cur converts/stores
    }
    FLUSH(cur)
  }
#undef ADDR
#undef ISSUE
#undef FLUSH
}

// ---------------- prep: CW, cbias, W1bf ----------------
__global__ __launch_bounds__(256) void prep_kernel(
    const float* __restrict__ down_W, const float* __restrict__ down_b,
    const float* __restrict__ merge_W, const float* __restrict__ merge_b,
    float* __restrict__ CW, float* __restrict__ cbias,
    unsigned short* __restrict__ W1bf) {
  int idx = blockIdx.x * 256 + threadIdx.x;
  if (idx < 32768) {
    int k = idx >> 7, o = idx & 127;  // CW[k][o] = sum_t down_W[t][k]*merge_W[o][128+t]
    float s = 0.f;
    #pragma unroll 4
    for (int t = 0; t < 128; ++t)
      s += down_W[t * 256 + k] * merge_W[o * 256 + 128 + t];
    CW[idx] = s;
  } else if (idx < 49152) {
    int i2 = idx - 32768;
    int n = i2 >> 7, c = i2 & 127;
    W1bf[i2] = f2bf(merge_W[n * 256 + c]);  // W1bf[n][c]
  } else if (idx < 49280) {
    int o = idx - 49152;
    float s = merge_b[o];
    #pragma unroll 4
    for (int t = 0; t < 128; ++t)
      s += down_b[t] * merge_W[o * 256 + 128 + t];
    cbias[o] = s;
  }
}

// ---------------- t2: coarse path (f32, proven) ----------------
__global__ __launch_bounds__(256) void t2_kernel(
    const float* __restrict__ c0, const float* __restrict__ c1,
    const int* __restrict__ b_ids, const int* __restrict__ i_ids,
    const int* __restrict__ j_ids,
    const float* __restrict__ CW, const float* __restrict__ cbias,
    float* __restrict__ t2, int M) {
  __shared__ float crow[8][256];
  const int t = threadIdx.x;
  const int m0 = blockIdx.x * 8;
  const int M2 = 2 * M;
  #pragma unroll
  for (int it = 0; it < 8; ++it) {
    int m = m0 + it;
    float v = 0.f;
    if (m < M2) {
      int b, pos;
      const float* src;
      if (m < M) { b = b_ids[m]; pos = i_ids[m]; src = c0; }
      else       { b = b_ids[m - M]; pos = j_ids[m - M]; src = c1; }
      v = src[((size_t)b * LPOS + pos) * 256 + t];
    }
    crow[it][t] = v;
  }
  __syncthreads();
  const int o = t & 127, half = t >> 7;
  const int r0 = half * 4;
  float a0 = 0.f, a1 = 0.f, a2 = 0.f, a3 = 0.f;
  #pragma unroll 4
  for (int k = 0; k < 256; ++k) {
    float wv = CW[k * 128 + o];
    a0 += crow[r0 + 0][k] * wv;
    a1 += crow[r0 + 1][k] * wv;
    a2 += crow[r0 + 2][k] * wv;
    a3 += crow[r0 + 3][k] * wv;
  }
  const float cb = cbias[o];
  if (m0 + r0 + 0 < M2) t2[(size_t)(m0 + r0 + 0) * 128 + o] = a0 + cb;
  if (m0 + r0 + 1 < M2) t2[(size_t)(m0 + r0 + 1) * 128 + o] = a1 + cb;
  if (m0 + r0 + 2 < M2) t2[(size_t)(m0 + r0 + 2) * 128 + o] = a2 + cb;
  if (m0 + r0 + 3 < M2) t2[(size_t)(m0 + r0 + 3) * 128 + o] = a3 + cb;
}

// ---------------- fine: MFMA ----------------
// 4 waves/block, 1 m per wave. A global->reg in frag layout; B in swizzled LDS.
__global__ __launch_bounds__(256) void fine_mfma_kernel(
    const unsigned short* __restrict__ t0, const unsigned short* __restrict__ t1,
    const int* __restrict__ b_ids, const int* __restrict__ i_ids,
    const int* __restrict__ j_ids,
    const unsigned short* __restrict__ W1bf, const float* __restrict__ t2,
    float* __restrict__ out, int M) {
  __shared__ unsigned short Bl[128 * 128];  // swizzled [n][c] bf16, 32KB
  const int t = threadIdx.x;

  // stage B: rows n of W1bf, 16B chunks, XOR swizzle kb ^ ((n&7)<<4)
  #pragma unroll
  for (int it = 0; it < 8; ++it) {
    int q = it * 256 + t;
    int n = q >> 4;
    int kb16 = (q & 15) * 16;
    short8 v = *(const short8*)&W1bf[n * 128 + (q & 15) * 8];
    int dstB = n * 256 + (kb16 ^ ((n & 7) << 4));
    *(short8*)((char*)Bl + dstB) = v;
  }

  const int wid = t >> 6, lane = t & 63;
  const int lr = lane & 15, lg = lane >> 4;
  const int m = blockIdx.x * 4 + wid;
  const int M2 = 2 * M;
  const bool active = (m < M2);

  // A-fragments: lane holds window[p = mt*16+lr][k = kk*32 + lg*8 + 0..7]
  // tmap layout [b][c8][pix][8]: channels kk*32+lg*8.. are plane c8=kk*4+lg.
  short8 a[2][4];
  short8 az = {};
  if (active) {
    int b, pos;
    const unsigned short* tm;
    if (m < M) { b = b_ids[m]; pos = i_ids[m]; tm = t0; }
    else       { int mm = m - M; b = b_ids[mm]; pos = j_ids[mm]; tm = t1; }
    tm += (size_t)b * 16 * HWF * 8;
    int hc = pos / 80, wc = pos - hc * 80;
    int h0 = hc * 4 - 2, w0 = wc * 4 - 2;
    #pragma unroll
    for (int mt = 0; mt < 2; ++mt) {
      int p = mt * 16 + lr;
      int pr = p / 5;
      int hh = h0 + pr, ww = w0 + (p - pr * 5);
      bool valid = (p < 25) && ((unsigned)hh < (unsigned)HF) && ((unsigned)ww < (unsigned)WF);
      int px = valid ? (hh * WF + ww) : 0;
      #pragma unroll
      for (int kk = 0; kk < 4; ++kk) {
        const short8* ap =
            (const short8*)(tm + (((size_t)(kk * 4 + lg) * HWF + px) << 3));
        a[mt][kk] = valid ? *ap : az;
      }
    }
  } else {
    #pragma unroll
    for (int mt = 0; mt < 2; ++mt)
      #pragma unroll
      for (int kk = 0; kk < 4; ++kk) a[mt][kk] = az;
  }

  __syncthreads();
  if (!active) return;

  f32x4 acc[2][8];
  #pragma unroll
  for (int mt = 0; mt < 2; ++mt)
    #pragma unroll
    for (int nt = 0; nt < 8; ++nt) {
      f32x4 z = {0.f, 0.f, 0.f, 0.f};
      acc[mt][nt] = z;
    }

  #pragma unroll
  for (int nt = 0; nt < 8; ++nt) {
    int n = nt * 16 + lr;
    int kbase = n * 256;
    int sw = (n & 7) << 4;
    short8 bfr[4];
    #pragma unroll
    for (int kk = 0; kk < 4; ++kk) {
      int kb = (kk * 64 + lg * 16) ^ sw;
      bfr[kk] = *(const short8*)((const char*)Bl + kbase + kb);
    }
    #pragma unroll
    for (int kk = 0; kk < 4; ++kk) {
      acc[0][nt] = __builtin_amdgcn_mfma_f32_16x16x32_bf16(a[0][kk], bfr[kk], acc[0][nt], 0, 0, 0);
      acc[1][nt] = __builtin_amdgcn_mfma_f32_16x16x32_bf16(a[1][kk], bfr[kk], acc[1][nt], 0, 0, 0);
    }
  }

  // epilogue: D row = mt*16 + lg*4 + j (skip rows >= 25), col = nt*16 + lr.
  // Non-temporal: out is write-once, never re-read -> don't allocate in L2/L3.
  const float* t2row = t2 + (size_t)m * 128;
  float* orow = out + (size_t)m * 25 * 128;
  #pragma unroll
  for (int nt = 0; nt < 8; ++nt) {
    int o = nt * 16 + lr;
    float tv = t2row[o];
    #pragma unroll
    for (int mt = 0; mt < 2; ++mt) {
      #pragma unroll
      for (int j = 0; j < 4; ++j) {
        int r = mt * 16 + lg * 4 + j;
        if (r < 25)
          __builtin_nontemporal_store(acc[mt][nt][j] + tv, &orow[r * 128 + o]);
      }
    }
  }
}

extern "C" void kernel_launch(void* const* d_in, const int* in_sizes, int n_in,
                              void* d_out, int out_size, void* d_ws, size_t ws_size,
                              hipStream_t stream) {
  const float* f0      = (const float*)d_in[0];
  const float* f1      = (const float*)d_in[1];
  const float* c0      = (const float*)d_in[2];
  const float* c1      = (const float*)d_in[3];
  const int*   b_ids   = (const int*)d_in[6];
  const int*   i_ids   = (const int*)d_in[7];
  const int*   j_ids   = (const int*)d_in[8];
  const float* down_W  = (const float*)d_in[9];
  const float* down_b  = (const float*)d_in[10];
  const float* merge_W = (const float*)d_in[11];
  const float* merge_b = (const float*)d_in[12];
  const int M = in_sizes[6];
  const int M2 = 2 * M;

  char* wsb = (char*)d_ws;
  float* CW    = (float*)wsb;                 // 131072 B
  float* cbias = (float*)(wsb + 131072);      // 512 B
  float* t2    = (float*)(wsb + 131584);      // 2M*128*4 B
  size_t off = 131584 + (size_t)M2 * 128 * 4;
  off = (off + 255) & ~(size_t)255;
  unsigned short* W1bf = (unsigned short*)(wsb + off);  // 32768 B
  off += 32768;
  unsigned short* t0 = (unsigned short*)(wsb + off);    // 2*16*HWF*8*2 B
  off += (size_t)2 * 16 * HWF * 8 * 2;
  unsigned short* t1 = (unsigned short*)(wsb + off);

  transpose_kernel<<<2400, 256, 0, stream>>>(f0, f1, t0, t1);
  prep_kernel<<<193, 256, 0, stream>>>(down_W, down_b, merge_W, merge_b,
                                       CW, cbias, W1bf);
  t2_kernel<<<(M2 + 7) / 8, 256, 0, stream>>>(c0, c1, b_ids, i_ids, j_ids,
                                              CW, cbias, t2, M);
  fine_mfma_kernel<<<(M2 + 3) / 4, 256, 0, stream>>>(t0, t1, b_ids, i_ids, j_ids,
                                                     W1bf, t2, (float*)d_out, M);
}